// Round 8
// baseline (648.889 us; speedup 1.0000x reference)
//
#include <hip/hip_runtime.h>
#include <math.h>

constexpr int kH  = 4;
constexpr int kHD = 32;
constexpr int kC  = 128;
constexpr int kNU = 40000;
constexpr int kNI = 40000;
constexpr int kE  = 200000;
constexpr int kNT = kNU + kNI;
constexpr int kTS = 1 << 19;             // hash table slots (load factor 0.38)
constexpr int kTMASK = kTS - 1;
constexpr int kSB = (kNT + 1023) / 1024; // scan blocks = 79
constexpr int kTilesPerSide = kNU / 16;  // 2500
constexpr int kTiles = kNT / 16;         // 5000
constexpr int kGrid = 1250;              // gemm grid (4 tiles/block)
constexpr int kCap = 128;                // per-node esc LDS capacity
constexpr int kLQ = 136;                 // qkv LDS row stride (bf16; 128+8 pad)
constexpr int kLW = 132;                 // wo_ln LDS row stride (f32; 128+4 pad)

#define DEV_INLINE __device__ __forceinline__

typedef short bf16x8 __attribute__((ext_vector_type(8)));   // 8 bf16 in 4 VGPRs
typedef float f32x4  __attribute__((ext_vector_type(4)));

DEV_INLINE int hash_slot(int pid) {
  uint32_t h = (uint32_t)pid * 2654435761u;
  return (int)((h >> 13) & kTMASK);
}

DEV_INLINE unsigned short f2bf(float f) {          // RNE float->bf16
  uint32_t u = __float_as_uint(f);
  u += 0x7fffu + ((u >> 16) & 1u);
  return (unsigned short)(u >> 16);
}

DEV_INLINE float bflo(uint32_t u) { return __uint_as_float(u << 16); }
DEV_INLINE float bfhi(uint32_t u) { return __uint_as_float(u & 0xffff0000u); }

// load 8 consecutive fp32 -> bf16x8 fragment
DEV_INLINE bf16x8 ld_frag_f32(const float* p) {
  float4 a = *(const float4*)p;
  float4 b = *(const float4*)(p + 4);
  bf16x8 r;
  r[0] = (short)f2bf(a.x); r[1] = (short)f2bf(a.y);
  r[2] = (short)f2bf(a.z); r[3] = (short)f2bf(a.w);
  r[4] = (short)f2bf(b.x); r[5] = (short)f2bf(b.y);
  r[6] = (short)f2bf(b.z); r[7] = (short)f2bf(b.w);
  return r;
}

// ---------------------------------------------------------------------------
// Fused QKV projection, both node types. Reads x and W in fp32 directly
// (no cast pass). Weight-stationary in registers; wave owns 2 of 8 col-tiles.
// Epilogue: frags -> padded LDS -> fully-coalesced 16B/thread stores
// (round-7 counters: direct frag stores = 16x32B segments, transaction-bound).
// ---------------------------------------------------------------------------
__global__ __launch_bounds__(256, 3) void qkv_ws(
    const float* __restrict__ Xu, const float* __restrict__ Xi,
    const float* __restrict__ Wq, const float* __restrict__ Wk,
    const float* __restrict__ Wv,
    const float* __restrict__ bq, const float* __restrict__ bk,
    const float* __restrict__ bv,
    unsigned short* __restrict__ Qu, unsigned short* __restrict__ Ku,
    unsigned short* __restrict__ Vu,
    unsigned short* __restrict__ Qi, unsigned short* __restrict__ Ki,
    unsigned short* __restrict__ Vi) {
  __shared__ __align__(16) unsigned short wl[3 * 16 * kLQ];   // 13056 B
  const int tid  = threadIdx.x;
  const int wave = tid >> 6;
  const int lane = tid & 63;
  const int mr   = lane & 15;
  const int quad = lane >> 4;
  const int ct0  = wave * 2;

  // stationary W fragments (fp32 -> bf16 once per block)
  bf16x8 wf[3][2][4];
  {
    const float* Ws[3] = {Wq, Wk, Wv};
#pragma unroll
    for (int m = 0; m < 3; ++m)
#pragma unroll
      for (int c = 0; c < 2; ++c) {
        const float* wrow = Ws[m] + (size_t)((ct0 + c) * 16 + mr) * kC + quad * 8;
#pragma unroll
        for (int kc = 0; kc < 4; ++kc) wf[m][c][kc] = ld_frag_f32(wrow + kc * 32);
      }
  }
  const float* bs[3] = {bq, bk, bv};
  const int crow = tid >> 4;      // cooperative-store row 0..15
  const int ccg  = tid & 15;      // cooperative-store 8-chan group

  for (int tile = blockIdx.x; tile < kTiles; tile += kGrid) {
    const bool item = tile >= kTilesPerSide;
    const int trow = (item ? tile - kTilesPerSide : tile);
    const int row  = trow * 16 + mr;
    const float* X = item ? Xi : Xu;

    bf16x8 b[4];
    const float* xrow = X + (size_t)row * kC + quad * 8;
#pragma unroll
    for (int kc = 0; kc < 4; ++kc) b[kc] = ld_frag_f32(xrow + kc * 32);

    f32x4 acc[3][2];
#pragma unroll
    for (int m = 0; m < 3; ++m) {
      acc[m][0] = (f32x4){0.f, 0.f, 0.f, 0.f};
      acc[m][1] = (f32x4){0.f, 0.f, 0.f, 0.f};
    }
#pragma unroll
    for (int kc = 0; kc < 4; ++kc)
#pragma unroll
      for (int m = 0; m < 3; ++m)
#pragma unroll
        for (int c = 0; c < 2; ++c)
          acc[m][c] = __builtin_amdgcn_mfma_f32_16x16x32_bf16(wf[m][c][kc], b[kc], acc[m][c], 0, 0, 0);

    // frags -> LDS (lane mr owns node-row mr, chans (ct0+c)*16+quad*4..+3)
#pragma unroll
    for (int m = 0; m < 3; ++m)
#pragma unroll
      for (int c = 0; c < 2; ++c) {
        int c0 = (ct0 + c) * 16 + quad * 4;
        float4 bb = *(const float4*)(bs[m] + c0);
        uint2 p;
        p.x = (uint32_t)f2bf(acc[m][c][0] + bb.x) | ((uint32_t)f2bf(acc[m][c][1] + bb.y) << 16);
        p.y = (uint32_t)f2bf(acc[m][c][2] + bb.z) | ((uint32_t)f2bf(acc[m][c][3] + bb.w) << 16);
        *(uint2*)(wl + m * 16 * kLQ + mr * kLQ + c0) = p;
      }
    __syncthreads();

    // coalesced store: thread t -> row t>>4, chans (t&15)*8..+7 (16 B)
    unsigned short* Os[3] = {item ? Qi : Qu, item ? Ki : Ku, item ? Vi : Vu};
#pragma unroll
    for (int m = 0; m < 3; ++m) {
      uint4 v = *(const uint4*)(wl + m * 16 * kLQ + crow * kLQ + ccg * 8);
      *(uint4*)(Os[m] + (size_t)(trow * 16 + crow) * kC + ccg * 8) = v;
    }
    __syncthreads();   // protect wl before next tile
  }
}

// ---------------------------------------------------------------------------
// Hash insert for BOTH relations in one launch: pid = src*mulN + dst;
// also count relation in-degree into deg_all ([item | user]).
// ---------------------------------------------------------------------------
__global__ void build_table2(const int* __restrict__ su, const int* __restrict__ du,
                             const int* __restrict__ si, const int* __restrict__ di,
                             int* __restrict__ keyA, int* __restrict__ cntA,
                             int* __restrict__ keyB, int* __restrict__ cntB,
                             int* __restrict__ deg_all) {
  int i = blockIdx.x * blockDim.x + threadIdx.x;
  if (i >= 2 * kE) return;
  int s, d, pid; int* keys; int* cnt; int* deg;
  if (i < kE) { s = su[i]; d = du[i]; pid = s * kNI + d; keys = keyA; cnt = cntA; deg = deg_all + d; }
  else { int j = i - kE; s = si[j]; d = di[j]; pid = s * kNU + d; keys = keyB; cnt = cntB; deg = deg_all + kNI + d; }
  int slot = hash_slot(pid);
  for (;;) {
    int old = atomicCAS(&keys[slot], -1, pid);
    if (old == -1 || old == pid) { atomicAdd(&cnt[slot], 1); break; }
    slot = (slot + 1) & kTMASK;
  }
  atomicAdd(deg, 1);
}

DEV_INLINE int table_count(const int* __restrict__ keys, const int* __restrict__ cnt, int pid) {
  int slot = hash_slot(pid);
  for (;;) {
    int k = keys[slot];
    if (k == pid) return cnt[slot];
    if (k == -1) return 0;
    slot = (slot + 1) & kTMASK;
  }
}

// ---------------------------------------------------------------------------
// Device-wide exclusive scan, 3 phases.
// ---------------------------------------------------------------------------
__global__ __launch_bounds__(256) void scan1(const int* __restrict__ in,
                                             int* __restrict__ out,
                                             int* __restrict__ bsum, int n) {
  __shared__ int sh[256];
  const int t = threadIdx.x;
  const int base = blockIdx.x * 1024 + t * 4;
  int4 v = {0, 0, 0, 0};
  if (base + 3 < n) {
    v = *(const int4*)(in + base);
  } else {
    if (base + 0 < n) v.x = in[base + 0];
    if (base + 1 < n) v.y = in[base + 1];
    if (base + 2 < n) v.z = in[base + 2];
    if (base + 3 < n) v.w = in[base + 3];
  }
  int s = v.x + v.y + v.z + v.w;
  sh[t] = s;
  __syncthreads();
  int val = s;
  for (int off = 1; off < 256; off <<= 1) {
    int add = (t >= off) ? sh[t - off] : 0;
    __syncthreads();
    val += add;
    sh[t] = val;
    __syncthreads();
  }
  int excl = val - s;
  if (base + 0 < n) out[base + 0] = excl;
  if (base + 1 < n) out[base + 1] = excl + v.x;
  if (base + 2 < n) out[base + 2] = excl + v.x + v.y;
  if (base + 3 < n) out[base + 3] = excl + v.x + v.y + v.z;
  if (t == 255) bsum[blockIdx.x] = val;
}

__global__ __launch_bounds__(128) void scan2(const int* __restrict__ bsum,
                                             int* __restrict__ boff,
                                             int* __restrict__ out_total, int nb) {
  __shared__ int sh[128];
  const int t = threadIdx.x;
  int v = (t < nb) ? bsum[t] : 0;
  sh[t] = v;
  __syncthreads();
  int val = v;
  for (int off = 1; off < 128; off <<= 1) {
    int add = (t >= off) ? sh[t - off] : 0;
    __syncthreads();
    val += add;
    sh[t] = val;
    __syncthreads();
  }
  if (t < nb) boff[t] = val - v;
  if (t == nb - 1) *out_total = val;
}

__global__ __launch_bounds__(256) void scan3(int* __restrict__ out,
                                             const int* __restrict__ boff, int n) {
  const int base = blockIdx.x * 1024 + threadIdx.x * 4;
  const int off = boff[blockIdx.x];
#pragma unroll
  for (int i = 0; i < 4; ++i)
    if (base + i < n) out[base + i] += off;
}

// ---------------------------------------------------------------------------
// CSR scatter, both relations: el_all[rp_all[node] + cursor++] = local edge id
// ---------------------------------------------------------------------------
__global__ void scatter2(const int* __restrict__ du, const int* __restrict__ di,
                         const int* __restrict__ rp_all, int* __restrict__ cur_all,
                         int* __restrict__ el_all) {
  int i = blockIdx.x * blockDim.x + threadIdx.x;
  if (i >= 2 * kE) return;
  int node, eid;
  if (i < kE) { node = du[i]; eid = i; }
  else { node = kNI + di[i - kE]; eid = i - kE; }
  int pos = atomicAdd(&cur_all[node], 1);
  el_all[rp_all[node] + pos] = eid;
}

// ---------------------------------------------------------------------------
// Fused attention: per dst node (1 wave each), both relations in one launch.
// Pass 1: scores (Q resident, K gathered 256B-coalesced per edge), bias via
// hash probes, z accumulated in registers, exp(score) cached in LDS (cap 128,
// recompute fallback). Pass 2: w = esc/z, V gathered, h row stored bf16.
// Replaces edge_bias + edge_scores + node_aggregate; no atomics, no esc/z/
// bias global buffers. Segment-max omitted: scores bounded (rounds 1-7).
// ---------------------------------------------------------------------------
__global__ __launch_bounds__(256) void fused_attn(
    const int* __restrict__ rp_all, const int* __restrict__ el_all,
    const int* __restrict__ su, const int* __restrict__ si,
    const unsigned short* __restrict__ Qu, const unsigned short* __restrict__ Ku,
    const unsigned short* __restrict__ Vu,
    const unsigned short* __restrict__ Qi, const unsigned short* __restrict__ Ki,
    const unsigned short* __restrict__ Vi,
    const float* __restrict__ t_user, const float* __restrict__ t_item,
    const int* __restrict__ keyA, const int* __restrict__ cntA,
    const int* __restrict__ keyB, const int* __restrict__ cntB,
    const float* __restrict__ hb, const float* __restrict__ beta,
    const float* __restrict__ taur, const float* __restrict__ gamma,
    const float* __restrict__ delta,
    unsigned short* __restrict__ h_ui, unsigned short* __restrict__ h_iu) {
  __shared__ float esc_sh[4][kCap][4];
  const int wave = threadIdx.x >> 6;
  const int lane = threadIdx.x & 63;
  const int h    = lane >> 4;
  const int nn   = blockIdx.x * 4 + wave;
  if (nn >= kNT) return;

  const bool iu = nn >= kNI;          // second relation (item->user)
  const int n = iu ? nn - kNI : nn;
  const int rel = iu ? 1 : 0;
  const int* srcA = iu ? si : su;
  const unsigned short* Q = iu ? Qu : Qi;
  const unsigned short* K = iu ? Ki : Ku;
  const unsigned short* V = iu ? Vi : Vu;
  const float* t_src = iu ? t_item : t_user;
  const float td = iu ? t_user[n] : t_item[n];
  const int* keysC = iu ? keyB : keyA;  const int* cntC = iu ? cntB : cntA;
  const int* keysR = iu ? keyA : keyB;  const int* cntR = iu ? cntA : cntB;
  const int mulC = iu ? kNU : kNI;
  const int mulR = iu ? kNI : kNU;
  unsigned short* Hout = iu ? h_iu : h_ui;

  const int beg = rp_all[nn], end = rp_all[nn + 1];

  // per-lane head params
  const float hbh    = hb[rel * kH + h];
  const float betah  = beta[rel * kH + h];
  const float gammah = gamma[rel * kH + h];
  const float deltah = delta[rel * kH + h];
  const float tau    = log1pf(expf(taur[rel])) + 1e-6f;

  // resident Q: lane owns chans lane*2, lane*2+1 (head = lane>>4)
  uint32_t q32 = *(const uint32_t*)(Q + (size_t)n * kC + lane * 2);
  const float q0 = bflo(q32), q1 = bfhi(q32);

  float zacc = 0.0f;
  // ---- pass 1: scores, z, cache exp(score) ----
  for (int p0 = beg; p0 < end; p0 += 64) {
    int cnt = min(64, end - p0);
    int el = 0, sl = 0;
    if (lane < cnt) { el = el_all[p0 + lane]; sl = srcA[el]; }
    for (int j = 0; j < cnt; ++j) {
      int s = __shfl(sl, j, 64);
      uint32_t k32 = *(const uint32_t*)(K + (size_t)s * kC + lane * 2);
      float prod = q0 * bflo(k32) + q1 * bfhi(k32);
      prod += __shfl_xor(prod, 1, 16);
      prod += __shfl_xor(prod, 2, 16);
      prod += __shfl_xor(prod, 4, 16);
      prod += __shfl_xor(prod, 8, 16);
      float cv  = (float)(table_count(keysC, cntC, s * mulC + n) - 1);
      float rec = table_count(keysR, cntR, n * mulR + s) > 0 ? 1.0f : 0.0f;
      float dt  = fabsf(td - t_src[s]) + 1e-6f;
      float sc  = prod * 0.17677669529663687f + hbh
                + betah * (-log1pf(dt / tau)) + gammah * log1pf(cv) + deltah * rec;
      float es = expf(sc);
      zacc += es;
      int ii = p0 + j - beg;
      if (ii < kCap && (lane & 15) == 0) esc_sh[wave][ii][h] = es;
    }
  }

  // ---- pass 2: aggregate V with w = esc/z ----
  const float zi = (beg < end) ? 1.0f / zacc : 0.0f;
  float a0 = 0.0f, a1 = 0.0f;
  for (int p0 = beg; p0 < end; p0 += 64) {
    int cnt = min(64, end - p0);
    int el = 0, sl = 0;
    if (lane < cnt) { el = el_all[p0 + lane]; sl = srcA[el]; }
    for (int j = 0; j < cnt; ++j) {
      int s = __shfl(sl, j, 64);
      int ii = p0 + j - beg;
      float es;
      if (ii < kCap) {
        es = esc_sh[wave][ii][h];
      } else {                        // cold fallback: recompute score
        uint32_t k32 = *(const uint32_t*)(K + (size_t)s * kC + lane * 2);
        float prod = q0 * bflo(k32) + q1 * bfhi(k32);
        prod += __shfl_xor(prod, 1, 16);
        prod += __shfl_xor(prod, 2, 16);
        prod += __shfl_xor(prod, 4, 16);
        prod += __shfl_xor(prod, 8, 16);
        float cv  = (float)(table_count(keysC, cntC, s * mulC + n) - 1);
        float rec = table_count(keysR, cntR, n * mulR + s) > 0 ? 1.0f : 0.0f;
        float dt  = fabsf(td - t_src[s]) + 1e-6f;
        es = expf(prod * 0.17677669529663687f + hbh
                  + betah * (-log1pf(dt / tau)) + gammah * log1pf(cv) + deltah * rec);
      }
      float wgt = es * zi;
      uint32_t v32 = *(const uint32_t*)(V + (size_t)s * kC + lane * 2);
      a0 = fmaf(bflo(v32), wgt, a0);
      a1 = fmaf(bfhi(v32), wgt, a1);
    }
  }
  uint32_t packed = (uint32_t)f2bf(a0) | ((uint32_t)f2bf(a1) << 16);
  *(uint32_t*)(Hout + (size_t)n * kC + lane * 2) = packed;
}

// ---------------------------------------------------------------------------
// Fused Wo GEMM + residual + LayerNorm, both sides. tmp lives only in LDS.
// out = LN(x + Wo@h + deg*bo)  (degree-centrality row-constant cancels in LN).
// ---------------------------------------------------------------------------
__global__ __launch_bounds__(256, 4) void wo_ln(
    const unsigned short* __restrict__ Hiu, const unsigned short* __restrict__ Hui,
    const float* __restrict__ Wo, const float* __restrict__ bo,
    const float* __restrict__ Xu, const float* __restrict__ Xi,
    const int* __restrict__ deg_all,
    float* __restrict__ out) {
  __shared__ __align__(16) float tl[16 * kLW];    // 8448 B
  const int tid  = threadIdx.x;
  const int wave = tid >> 6;
  const int lane = tid & 63;
  const int mr   = lane & 15;
  const int quad = lane >> 4;
  const int ct0  = wave * 2;
  const int crow = tid >> 4;
  const int ccg  = tid & 15;

  bf16x8 wf[2][4];
#pragma unroll
  for (int c = 0; c < 2; ++c) {
    const float* wrow = Wo + (size_t)((ct0 + c) * 16 + mr) * kC + quad * 8;
#pragma unroll
    for (int kc = 0; kc < 4; ++kc) wf[c][kc] = ld_frag_f32(wrow + kc * 32);
  }

  for (int tile = blockIdx.x; tile < kTiles; tile += kGrid) {
    const bool item = tile >= kTilesPerSide;
    const int trow = item ? tile - kTilesPerSide : tile;
    const unsigned short* Hrow = (item ? Hui : Hiu) + (size_t)(trow * 16 + mr) * kC + quad * 8;

    bf16x8 b[4];
#pragma unroll
    for (int kc = 0; kc < 4; ++kc) b[kc] = *(const bf16x8*)(Hrow + kc * 32);

    f32x4 acc[2];
    acc[0] = (f32x4){0.f, 0.f, 0.f, 0.f};
    acc[1] = (f32x4){0.f, 0.f, 0.f, 0.f};
#pragma unroll
    for (int kc = 0; kc < 4; ++kc)
#pragma unroll
      for (int c = 0; c < 2; ++c)
        acc[c] = __builtin_amdgcn_mfma_f32_16x16x32_bf16(wf[c][kc], b[kc], acc[c], 0, 0, 0);

#pragma unroll
    for (int c = 0; c < 2; ++c) {
      int c0 = (ct0 + c) * 16 + quad * 4;
      *(float4*)(tl + mr * kLW + c0) = (float4){acc[c][0], acc[c][1], acc[c][2], acc[c][3]};
    }
    __syncthreads();

    // LN over the 16 rows: thread -> row crow, chans ccg*8..+7
    const float* x = (item ? Xi : Xu) + (size_t)(trow * 16 + crow) * kC + ccg * 8;
    float dg = (float)deg_all[(item ? 0 : kNI) + trow * 16 + crow];
    float y[8];
    float s1 = 0.f, s2 = 0.f;
#pragma unroll
    for (int j = 0; j < 8; ++j) {
      float t = tl[crow * kLW + ccg * 8 + j];
      float v = x[j] + t + dg * bo[ccg * 8 + j];
      y[j] = v; s1 += v; s2 += v * v;
    }
    s1 += __shfl_xor(s1, 1, 16); s2 += __shfl_xor(s2, 1, 16);
    s1 += __shfl_xor(s1, 2, 16); s2 += __shfl_xor(s2, 2, 16);
    s1 += __shfl_xor(s1, 4, 16); s2 += __shfl_xor(s2, 4, 16);
    s1 += __shfl_xor(s1, 8, 16); s2 += __shfl_xor(s2, 8, 16);
    float mu  = s1 * (1.0f / 128.0f);
    float var = s2 * (1.0f / 128.0f) - mu * mu;
    float rs  = rsqrtf(fmaxf(var, 0.0f) + 1e-5f);
    float* op = out + (item ? (size_t)kNU * kC : 0) + (size_t)(trow * 16 + crow) * kC + ccg * 8;
#pragma unroll
    for (int j = 0; j < 8; ++j) op[j] = (y[j] - mu) * rs;
    __syncthreads();
  }
}

// ---------------------------------------------------------------------------
extern "C" void kernel_launch(void* const* d_in, const int* in_sizes, int n_in,
                              void* d_out, int out_size, void* d_ws, size_t ws_size,
                              hipStream_t stream) {
  const float* x_user = (const float*)d_in[0];
  const float* x_item = (const float*)d_in[1];
  const float* t_user = (const float*)d_in[2];
  const float* t_item = (const float*)d_in[3];
  const int*   eui    = (const int*)d_in[4];
  const int*   eiu    = (const int*)d_in[5];
  const float* Wq = (const float*)d_in[6];
  const float* bq = (const float*)d_in[7];
  const float* Wk = (const float*)d_in[8];
  const float* bk = (const float*)d_in[9];
  const float* Wv = (const float*)d_in[10];
  const float* bv = (const float*)d_in[11];
  const float* Wo = (const float*)d_in[12];
  const float* bo = (const float*)d_in[13];
  const float* hb    = (const float*)d_in[14];
  const float* beta  = (const float*)d_in[15];
  const float* taur  = (const float*)d_in[16];
  const float* gamma = (const float*)d_in[17];
  const float* delta = (const float*)d_in[18];

  const int* su = eui;       const int* du = eui + kE;   // user -> item
  const int* si = eiu;       const int* di = eiu + kE;   // item -> user

  float* w = (float*)d_ws;
  size_t o = 0;
  // bf16 buffers (offsets in float units = half the element count)
  unsigned short* qu_b = (unsigned short*)(w + o); o += (size_t)kNU * kC / 2;
  unsigned short* ku_b = (unsigned short*)(w + o); o += (size_t)kNU * kC / 2;
  unsigned short* vu_b = (unsigned short*)(w + o); o += (size_t)kNU * kC / 2;
  unsigned short* qi_b = (unsigned short*)(w + o); o += (size_t)kNI * kC / 2;
  unsigned short* ki_b = (unsigned short*)(w + o); o += (size_t)kNI * kC / 2;
  unsigned short* vi_b = (unsigned short*)(w + o); o += (size_t)kNI * kC / 2;
  unsigned short* h_ui = (unsigned short*)(w + o); o += (size_t)kNI * kC / 2;  // dst=item
  unsigned short* h_iu = (unsigned short*)(w + o); o += (size_t)kNU * kC / 2;  // dst=user
  // --- zero-init region ---
  float* zero_base = w + o;
  int*   cntA = (int*)(w + o); o += kTS;
  int*   cntB = (int*)(w + o); o += kTS;
  int* deg_all  = (int*)(w + o); o += kNT;   // [item deg | user deg]
  int* cur_all  = (int*)(w + o); o += kNT;
  size_t zero_bytes = (size_t)((w + o) - zero_base) * sizeof(float);
  // --- 0xFF-init region (empty hash keys) ---
  int* keyA = (int*)(w + o); o += kTS;
  int* keyB = (int*)(w + o); o += kTS;
  size_t key_bytes = (size_t)2 * kTS * sizeof(int);
  // --- no-init region ---
  int* rp_all = (int*)(w + o); o += kNT + 1;   // combined rowptr (item | user)
  int* el_all = (int*)(w + o); o += 2 * kE;    // combined edge list (local ids)
  int* bsum   = (int*)(w + o); o += kSB;
  int* boff   = (int*)(w + o); o += kSB;

  hipMemsetAsync(zero_base, 0, zero_bytes, stream);
  hipMemsetAsync(keyA, 0xFF, key_bytes, stream);

  dim3 b256(256);
  // fused QKV projection (fp32 in, bf16 out, coalesced epilogue)
  qkv_ws<<<kGrid, b256, 0, stream>>>(x_user, x_item, Wq, Wk, Wv, bq, bk, bv,
                                     qu_b, ku_b, vu_b, qi_b, ki_b, vi_b);

  int gE2 = (2 * kE + 255) / 256;
  build_table2<<<gE2, b256, 0, stream>>>(su, du, si, di, keyA, cntA, keyB, cntB, deg_all);

  // device-wide scan over [deg_item | deg_user] -> combined rowptr
  scan1<<<kSB, b256, 0, stream>>>(deg_all, rp_all, bsum, kNT);
  scan2<<<1, dim3(128), 0, stream>>>(bsum, boff, rp_all + kNT, kSB);
  scan3<<<kSB, b256, 0, stream>>>(rp_all, boff, kNT);

  scatter2<<<gE2, b256, 0, stream>>>(du, di, rp_all, cur_all, el_all);

  // fused scores + softmax + aggregation, both relations
  fused_attn<<<(kNT + 3) / 4, b256, 0, stream>>>(
      rp_all, el_all, su, si, qu_b, ku_b, vu_b, qi_b, ki_b, vi_b,
      t_user, t_item, keyA, cntA, keyB, cntB,
      hb, beta, taur, gamma, delta, h_ui, h_iu);

  // fused Wo GEMM + residual + LayerNorm
  wo_ln<<<kGrid, b256, 0, stream>>>(h_iu, h_ui, Wo, bo, x_user, x_item,
                                    deg_all, (float*)d_out);
}